// Round 4
// baseline (759.697 us; speedup 1.0000x reference)
//
#include <hip/hip_runtime.h>
#include <stdint.h>

// LocallyConnected2D: out[b,f,or,oc] = relu( sum_{c,kh,kw} x[b,c,2or+kh,2oc+kw]*W[f,c,2or+kh,2oc+kw] + bias )
// bias raw-reshape: bias_flat[f*OR*OC + or*OC + oc]
//
// B=32 C=32 H=128 W=128 F=64 OR=OC=64.
//
// R8 vs R7 (98 us; VALU 22%, HBM 17%, 2.4x above the 41us LDS floor):
//  - W REMOVED from LDS. W's only reuse (8 threads per element) is INTRA-WAVE (bg=lane>>3),
//    which the coalescer serves free: 8-lane-dup global_load_dwordx4 = one 128-B line fetch
//    broadcast on return. LDS staging for W was pure overhead: half of all ds_read slots
//    were 8-way same-address broadcasts (1 KB LDS transaction for 128 useful bytes).
//    X stays in LDS (true 8-wave reuse), gload_lds + counted vmcnt + raw barriers (R7).
//  - W prefetched one chunk ahead into named ping-pong registers, pinned with
//    sched_barrier(0) clusters (NOT "memory" clobbers - R6 scratch disaster; NOT unpinned -
//    R5 sink). s0/s1 split clusters cap W liveness at ~48 VGPR -> total ~115 < 128 cap.
//  - Compiler inserts its own precise counted waits for wb uses (it models global loads AND
//    gload_lds; wb(it) use sits after cluster(it) so its count stays >=10 - no drain).
//  - Hand vmcnt before bar1 covers only X readiness. Pinned issue stream/iter:
//    A[4xW(it+1,s0)] B[4xW(it+1,s1)] C[1xX(it+4), after bar2]. Suffix after X(it):
//    it=0: 11, it=1: 19, it>=2: 24..27 -> use 11/19/24 (24 over-drains only retired loads).
//  - LDS 32 KB/block (4 x 8 KB X bufs), 2 blocks/CU, 16 waves/CU.

#define CC  32
#define HH  128
#define WWD 128
#define FF  64
#define ORR 64
#define OCC 64
#define NIT 32                 // chunks = channels
#define HW  (HH * WWD)         // 16384 floats per channel
#define CHW (CC * HH * WWD)    // 524288 floats per f plane

#define SB() __builtin_amdgcn_sched_barrier(0)

__global__ __launch_bounds__(512, 4) void lc2d_kernel(
    const float* __restrict__ x, const float* __restrict__ wgt,
    const float* __restrict__ bias, float* __restrict__ out)
{
    __shared__ __align__(16) float Xs[4][2048];   // 32 KB: 4-deep X chunk buffers

    const int tid  = threadIdx.x;
    const int id   = blockIdx.x;           // [0,512)
    const int fblk = id >> 8;              // which 32-f half
    const int low  = id & 255;
    // ids differing by 128 share 128-B output lines and the same XCD (128%8==0);
    // pair (id, id+256) shares the x tile on the same CU/XCD (256%8==0).
    const int oct = ((low & 1) << 1) | (low >> 7);   // 0..3 -> oc0 = oct*16
    const int orr = (low >> 1) & 63;
    const int w0  = oct * 32;                         // 32 w-floats, 128-B aligned
    const int h0  = orr * 2;

    const int lane = tid & 63;
    const int wv   = tid >> 6;        // wave 0..7
    const int chk  = lane & 7;        // 16-B chunk within a 128-B row
    const int sub  = lane >> 3;       // row within this wave's 8-row slot

    // ---- X staging: tile per chunk = 2kh x 32b x 32w = 2048 fl; LDS row r = kh*32+b.
    // wave wv stages rows [wv*8, wv*8+8): ONE gload_lds (1 KB) per wave per chunk.
    const int r = wv * 8 + sub;
    const float* gx = x + ((((r & 31) * CC) * HH) + h0 + (r >> 5)) * WWD + w0 + chk * 4;

    auto issueX = [&](int p) {
        __builtin_amdgcn_global_load_lds(
            (const __attribute__((address_space(1))) void*)gx,
            (__attribute__((address_space(3))) void*)(&Xs[p][wv * 256]), 16, 0, 0);
        gx += HW;
    };

    // ---- compute mapping: ocg = w 4-float chunk (2 oc), bg -> 4 b, wv -> 4 f
    const int ocg = tid & 7;
    const int bg  = (tid >> 3) & 7;
    const int xoff = bg * 128 + ocg * 4;

    // W register loads for f = fblk*32 + wv*4 + q: 8 ocg-lanes x 16 B = one 128-B line,
    // duplicated across 8 bg-lanes (merged by the coalescer; zero cross-wave reuse -> no LDS).
    const float* wp = wgt + (size_t)(fblk * 32 + wv * 4) * CHW + (size_t)h0 * WWD + w0 + ocg * 4;

    float acc0[4][4], acc1[4][4];          // [i=b][q=f], oc even / oc odd
#pragma unroll
    for (int i = 0; i < 4; ++i)
#pragma unroll
        for (int q = 0; q < 4; ++q) { acc0[i][q] = 0.f; acc1[i][q] = 0.f; }

    // ---- prologue (pinned order: X0 X1 X2 X3 | W(0,s0)x4 W(0,s1)x4)
    issueX(0); issueX(1); issueX(2); issueX(3);
    SB();
    float4 wEs0[4], wEs1[4], wOs0[4], wOs1[4];
#pragma unroll
    for (int q = 0; q < 4; ++q) wEs0[q] = *(const float4*)(wp + q * CHW);
#pragma unroll
    for (int q = 0; q < 4; ++q) wEs1[q] = *(const float4*)(wp + q * CHW + WWD);
    SB();
    const float* wnx = wp + HW;            // W source for chunk it+1

#define CHUNK(IT, CS0, CS1, NS0, NS1)                                           \
    {                                                                           \
        const int it_ = (IT);                                                   \
        if (it_ == 0)      asm volatile("s_waitcnt vmcnt(11)");                 \
        else if (it_ == 1) asm volatile("s_waitcnt vmcnt(19)");                 \
        else               asm volatile("s_waitcnt vmcnt(24)");                 \
        SB();                                                                   \
        __builtin_amdgcn_s_barrier();      /* bar1: X(it) visible, no drain */  \
        SB();                                                                   \
        if (it_ + 1 < NIT) {               /* cluster A: W(it+1, s0) */         \
            _Pragma("unroll")                                                   \
            for (int q = 0; q < 4; ++q) NS0[q] = *(const float4*)(wnx + q * CHW); \
        }                                                                       \
        SB();                                                                   \
        const float* Xp = &Xs[it_ & 3][0];                                      \
        {   /* s = 0 */                                                         \
            const float4* xr = (const float4*)(Xp + xoff);                      \
            float4 xa[4];                                                       \
            _Pragma("unroll")                                                   \
            for (int i = 0; i < 4; ++i) xa[i] = xr[i * 8];                      \
            _Pragma("unroll")                                                   \
            for (int i = 0; i < 4; ++i)                                         \
                _Pragma("unroll")                                               \
                for (int q = 0; q < 4; ++q) {                                   \
                    acc0[i][q] = fmaf(xa[i].x, CS0[q].x, acc0[i][q]);           \
                    acc0[i][q] = fmaf(xa[i].y, CS0[q].y, acc0[i][q]);           \
                    acc1[i][q] = fmaf(xa[i].z, CS0[q].z, acc1[i][q]);           \
                    acc1[i][q] = fmaf(xa[i].w, CS0[q].w, acc1[i][q]);           \
                }                                                               \
        }                                                                       \
        SB();                                                                   \
        if (it_ + 1 < NIT) {               /* cluster B: W(it+1, s1) */         \
            _Pragma("unroll")                                                   \
            for (int q = 0; q < 4; ++q) NS1[q] = *(const float4*)(wnx + q * CHW + WWD); \
        }                                                                       \
        SB();                                                                   \
        {   /* s = 1 */                                                         \
            const float4* xr = (const float4*)(Xp + 1024 + xoff);               \
            float4 xa[4];                                                       \
            _Pragma("unroll")                                                   \
            for (int i = 0; i < 4; ++i) xa[i] = xr[i * 8];                      \
            _Pragma("unroll")                                                   \
            for (int i = 0; i < 4; ++i)                                         \
                _Pragma("unroll")                                               \
                for (int q = 0; q < 4; ++q) {                                   \
                    acc0[i][q] = fmaf(xa[i].x, CS1[q].x, acc0[i][q]);           \
                    acc0[i][q] = fmaf(xa[i].y, CS1[q].y, acc0[i][q]);           \
                    acc1[i][q] = fmaf(xa[i].z, CS1[q].z, acc1[i][q]);           \
                    acc1[i][q] = fmaf(xa[i].w, CS1[q].w, acc1[i][q]);           \
                }                                                               \
        }                                                                       \
        SB();                                                                   \
        __builtin_amdgcn_s_barrier();      /* bar2: buf (it&3) free */          \
        SB();                                                                   \
        if (it_ + 4 < NIT) issueX(it_ & 3);  /* cluster C: X(it+4) */           \
        wnx += HW;                                                              \
    }

    for (int ih = 0; ih < NIT / 2; ++ih) {
        CHUNK(2 * ih,     wEs0, wEs1, wOs0, wOs1);   // even: use E, prefetch O
        CHUNK(2 * ih + 1, wOs0, wOs1, wEs0, wEs1);   // odd:  use O, prefetch E
    }
#undef CHUNK

    // ---- epilogue: bias (raw reshape [F][OR][OC]) + relu, float2 per (b,f)
    const int oc0 = oct * 16 + ocg * 2;
#pragma unroll
    for (int q = 0; q < 4; ++q) {
        const int f = fblk * 32 + wv * 4 + q;
        const float2 bv = *(const float2*)(bias + f * (ORR * OCC) + orr * OCC + oc0);
#pragma unroll
        for (int i = 0; i < 4; ++i) {
            const int b = bg * 4 + i;
            float2 o;
            o.x = fmaxf(acc0[i][q] + bv.x, 0.f);
            o.y = fmaxf(acc1[i][q] + bv.y, 0.f);
            *(float2*)(out + (((b * FF + f) * ORR + orr) * OCC) + oc0) = o;
        }
    }
}

extern "C" void kernel_launch(void* const* d_in, const int* in_sizes, int n_in,
                              void* d_out, int out_size, void* d_ws, size_t ws_size,
                              hipStream_t stream) {
    (void)in_sizes; (void)n_in; (void)d_ws; (void)ws_size; (void)out_size;
    const float* x    = (const float*)d_in[0];
    const float* wgt  = (const float*)d_in[1];
    const float* bias = (const float*)d_in[2];
    float* out        = (float*)d_out;
    lc2d_kernel<<<dim3(512, 1, 1), dim3(512, 1, 1), 0, stream>>>(x, wgt, bias, out);
}

// Round 5
// 263.363 us; speedup vs baseline: 2.8846x; 2.8846x over previous
//
#include <hip/hip_runtime.h>
#include <stdint.h>

// LocallyConnected2D: out[b,f,or,oc] = relu( sum_{c,kh,kw} x[b,c,2or+kh,2oc+kw]*W[f,c,2or+kh,2oc+kw] + bias )
// bias raw-reshape: bias_flat[f*OR*OC + or*OC + oc]
//
// B=32 C=32 H=128 W=128 F=64 OR=OC=64.
//
// R9 = R7 (98 us, counted-vmcnt 4-deep pipeline, X+W in LDS) + X bank-conflict fix.
//  - R8 post-mortem: W-in-registers spilled AGAIN (VGPR 64 + 1.27 GB scratch writes).
//    Register-pinned prefetch is abandoned on this shape; R7 structure restored.
//  - Diagnosis: SQ_LDS_BANK_CONFLICT = 4194304 bit-identical across ALL rounds = the xa
//    reads: lane addr = bg*512 + ocg*16 B; b-row stride 512 B == 0 mod 128-B bank span ->
//    all 8 bg-lanes on one bank quad -> 8-way conflict (~2.94x, m136). Model: 16 waves x
//    (8x35 + 8x12) cyc = 6.0k cyc/chunk ~= measured 7.3k. Conflicts ARE the bottleneck.
//  - Fix (rule #21: swizzle both sides or neither; LDS dest of global_load_lds is forced
//    linear): permute the per-lane GLOBAL source instead. Granule (b,chunk) of slice s
//    stored at position (b&3)*64 + (b>>2)*8 + chunk:
//      store: wave wv sources b = sub*4 + (wv&3)  (was (wv&3)*8 + sub)  -- one-line change
//      read:  xa[i] at float offset s*1024 + i*256 + lane*4  -- lane-linear, conflict-free
//    Same data -> same xa[i] -> identical FMA order -> bit-identical output.
//  - W path (8-way same-address broadcasts on distinct bank quads) already conflict-free.
// Verify: SQ_LDS_BANK_CONFLICT -> ~0; dur ~55-65 us; absmax unchanged.

#define CC  32
#define HH  128
#define WWD 128
#define FF  64
#define ORR 64
#define OCC 64
#define NIT 32                 // chunks = channels (CB=1)
#define HW  (HH * WWD)         // per-channel advance in floats
#define CHW (CC * HH * WWD)

__global__ __launch_bounds__(512, 4) void lc2d_kernel(
    const float* __restrict__ x, const float* __restrict__ wgt,
    const float* __restrict__ bias, float* __restrict__ out)
{
    // per chunk: X tile 2kh x 32b x 32w = 2048 floats; W half-tile 2kh x 32f x 32w = 2048
    __shared__ __align__(16) float Xs[4][2048];   // 32 KB
    __shared__ __align__(16) float Ws[4][2048];   // 32 KB  (64 KB total -> 2 blocks/CU)

    const int tid  = threadIdx.x;
    const int id   = blockIdx.x;           // [0,512)
    const int fblk = id >> 8;              // which 32-f half
    const int low  = id & 255;
    // ids differing by 128 share 128-B output lines and the same XCD (128%8==0).
    const int oct = ((low & 1) << 1) | (low >> 7);   // 0..3 -> oc0 = oct*16
    const int orr = (low >> 1) & 63;
    const int w0  = oct * 32;                         // 32 w-floats, 128-B aligned
    const int h0  = orr * 2;

    const int lane = tid & 63;
    const int wv   = tid >> 6;        // wave 0..7
    const int chk  = lane & 7;        // 16-B chunk within a 128-B row
    const int sub  = lane >> 3;       // row within this wave's 8-row slot

    // ---- staging pointers (chunk c=0).
    // X: slice s = wv>>2 (kh), wq = wv&3; lane (sub,chk) sources global row b = sub*4+wq,
    //    chunk chk. LDS dest linear (wv*256 + lane*4 floats) => granule (b,chk) lands at
    //    per-slice position (b&3)*64 + (b>>2)*8 + chk  -> lane-linear conflict-free reads.
    // W: row-major (fl = (wv&3)*8+sub), broadcast reads are conflict-free as-is.
    const int skh = wv >> 2;          // kh for this wave's slot
    const int bsw = sub * 4 + (wv & 3);               // swizzled b-row for X staging
    const int flr = (wv & 3) * 8 + sub;               // f-row for W staging
    const float* gx = x   + (((bsw * CC) * HH) + h0 + skh) * WWD + w0 + chk * 4;
    const float* gw = wgt + ((((fblk * 32 + flr) * CC) * HH) + h0 + skh) * WWD + w0 + chk * 4;

    auto issue = [&](int p) {
        __builtin_amdgcn_global_load_lds(
            (const __attribute__((address_space(1))) void*)gx,
            (__attribute__((address_space(3))) void*)(&Xs[p][wv * 256]), 16, 0, 0);
        __builtin_amdgcn_global_load_lds(
            (const __attribute__((address_space(1))) void*)gw,
            (__attribute__((address_space(3))) void*)(&Ws[p][wv * 256]), 16, 0, 0);
        gx += HW; gw += HW;           // next channel
    };

    // ---- compute mapping: ocg = w 4-float chunk (2 oc), bg -> 4 b, wv -> 4 f
    const int ocg = tid & 7;
    const int bg  = (tid >> 3) & 7;
    const int woff = wv * 128 + ocg * 4;   // W row wv*4, col ocg*4 (row-major layout)

    float acc0[4][4], acc1[4][4];          // [i=b][q=f], oc even / oc odd
#pragma unroll
    for (int i = 0; i < 4; ++i)
#pragma unroll
        for (int q = 0; q < 4; ++q) { acc0[i][q] = 0.f; acc1[i][q] = 0.f; }

    // prologue: 4 chunks in flight (8 loads/wave outstanding)
    issue(0); issue(1); issue(2); issue(3);

    for (int it = 0; it < NIT; ++it) {
        // wait for chunk `it`: loads newer than it = 2 * min(3, NIT-1-it)
        const int rem = NIT - 1 - it;
        if (rem >= 3)      asm volatile("s_waitcnt vmcnt(6)");
        else if (rem == 2) asm volatile("s_waitcnt vmcnt(4)");
        else if (rem == 1) asm volatile("s_waitcnt vmcnt(2)");
        else               asm volatile("s_waitcnt vmcnt(0)");
        __builtin_amdgcn_sched_barrier(0);
        __builtin_amdgcn_s_barrier();          // raw barrier: NO vmcnt(0) drain
        __builtin_amdgcn_sched_barrier(0);

        const int p = it & 3;
        const float* Xp = Xs[p];
        const float* Wp = Ws[p];
#pragma unroll
        for (int s = 0; s < 2; ++s) {          // kh
            // X swizzled layout: granule (b,chk) at position (b&3)*64 + (b>>2)*8 + chk.
            // This lane needs (b = bg*4+i, chk = ocg) -> float offset i*256 + lane*4:
            // lane-linear per i => conflict-free ds_read_b128.
            const float4* xr = (const float4*)(Xp + s * 1024 + (lane << 2));
            const float4* wr = (const float4*)(Wp + s * 1024 + woff);
            float4 xa[4], wb[4];
#pragma unroll
            for (int i = 0; i < 4; ++i) xa[i] = xr[i * 64];  // b = bg*4 + i
#pragma unroll
            for (int q = 0; q < 4; ++q) wb[q] = wr[q * 8];   // f = fblk*32 + wv*4 + q
#pragma unroll
            for (int i = 0; i < 4; ++i)
#pragma unroll
                for (int q = 0; q < 4; ++q) {
                    acc0[i][q] = fmaf(xa[i].x, wb[q].x, acc0[i][q]);
                    acc0[i][q] = fmaf(xa[i].y, wb[q].y, acc0[i][q]);
                    acc1[i][q] = fmaf(xa[i].z, wb[q].z, acc1[i][q]);
                    acc1[i][q] = fmaf(xa[i].w, wb[q].w, acc1[i][q]);
                }
        }
        __builtin_amdgcn_sched_barrier(0);
        __builtin_amdgcn_s_barrier();          // all waves done reading buf p
        __builtin_amdgcn_sched_barrier(0);
        if (it + 4 < NIT) issue(p);            // refill freed buffer; stays in flight
    }

    // ---- epilogue: bias (raw reshape [F][OR][OC]) + relu, float2 per (b,f)
    const int oc0 = oct * 16 + ocg * 2;
#pragma unroll
    for (int q = 0; q < 4; ++q) {
        const int f = fblk * 32 + wv * 4 + q;
        const float2 bv = *(const float2*)(bias + f * (ORR * OCC) + orr * OCC + oc0);
#pragma unroll
        for (int i = 0; i < 4; ++i) {
            const int b = bg * 4 + i;
            float2 o;
            o.x = fmaxf(acc0[i][q] + bv.x, 0.f);
            o.y = fmaxf(acc1[i][q] + bv.y, 0.f);
            *(float2*)(out + (((b * FF + f) * ORR + orr) * OCC) + oc0) = o;
        }
    }
}

extern "C" void kernel_launch(void* const* d_in, const int* in_sizes, int n_in,
                              void* d_out, int out_size, void* d_ws, size_t ws_size,
                              hipStream_t stream) {
    (void)in_sizes; (void)n_in; (void)d_ws; (void)ws_size; (void)out_size;
    const float* x    = (const float*)d_in[0];
    const float* wgt  = (const float*)d_in[1];
    const float* bias = (const float*)d_in[2];
    float* out        = (float*)d_out;
    lc2d_kernel<<<dim3(512, 1, 1), dim3(512, 1, 1), 0, stream>>>(x, wgt, bias, out);
}